// Round 7
// baseline (244.070 us; speedup 1.0000x reference)
//
#include <hip/hip_runtime.h>

typedef unsigned short u16;
typedef __bf16 bf16x8 __attribute__((ext_vector_type(8)));
typedef float f32x4 __attribute__((ext_vector_type(4)));

#define AS1 __attribute__((address_space(1)))
#define AS3 __attribute__((address_space(3)))

static __device__ __forceinline__ u16 f2bf(float f) {
  union { float f; unsigned u; } v; v.f = f;
  unsigned r = (v.u + 0x7fff + ((v.u >> 16) & 1)) >> 16;
  return (u16)r;
}

// x [B][258] f32 -> hx [B][256] bf16, phase [B] float2
__global__ void prep_x_kernel(const float* __restrict__ x, u16* __restrict__ hx,
                              float2* __restrict__ phase, int B) {
  int i = blockIdx.x * blockDim.x + threadIdx.x;
  int total = B * 128;
  if (i < total) {
    int row = i >> 7, k2 = (i & 127);
    const float2 v = *reinterpret_cast<const float2*>(x + (size_t)row * 258 + k2 * 2);
    u16 a = f2bf(v.x), b = f2bf(v.y);
    *reinterpret_cast<unsigned*>(hx + (size_t)row * 256 + k2 * 2) =
        (unsigned)a | ((unsigned)b << 16);
  }
  if (i < B) {
    phase[i] = *reinterpret_cast<const float2*>(x + (size_t)i * 258 + 256);
  }
}

// w [2][K][N] f32 -> wt [2][N][K] bf16 (plain transposed layout, for layer 3)
__global__ void prep_w_kernel(const float* __restrict__ w, u16* __restrict__ wt,
                              int K, int N) {
  __shared__ u16 tile[64][65];
  int k0 = blockIdx.x * 64, n0 = blockIdx.y * 64, mode = blockIdx.z;
  const float* src = w + (size_t)mode * K * N;
  u16* dst = wt + (size_t)mode * N * K;
  int c = threadIdx.x & 63;
  int r4 = threadIdx.x >> 6;
#pragma unroll
  for (int i = 0; i < 16; ++i) {
    int r = r4 + i * 4;
    tile[r][c] = f2bf(src[(size_t)(k0 + r) * N + n0 + c]);
  }
  __syncthreads();
#pragma unroll
  for (int i = 0; i < 16; ++i) {
    int r = r4 + i * 4;  // n index offset
    dst[(size_t)(n0 + r) * K + k0 + c] = tile[c][r];
  }
}

// w [2][K][N] f32 -> wt' [2N][K] bf16, mode-interleaved by 16-col groups:
// n' = (n>>4)*32 + mode*16 + (n&15)
__global__ void prep_w_int_kernel(const float* __restrict__ w, u16* __restrict__ wt,
                                  int K, int N) {
  __shared__ u16 tile[64][65];
  int k0 = blockIdx.x * 64, n0 = blockIdx.y * 64, mode = blockIdx.z;
  const float* src = w + (size_t)mode * K * N;
  int c = threadIdx.x & 63;
  int r4 = threadIdx.x >> 6;
#pragma unroll
  for (int i = 0; i < 16; ++i) {
    int r = r4 + i * 4;
    tile[r][c] = f2bf(src[(size_t)(k0 + r) * N + n0 + c]);
  }
  __syncthreads();
#pragma unroll
  for (int i = 0; i < 16; ++i) {
    int n = n0 + r4 + i * 4;
    int np = ((n >> 4) << 5) + (mode << 4) + (n & 15);
    wt[(size_t)np * K + k0 + c] = tile[c][r4 + i * 4];
  }
}

// ---------------------------------------------------------------------------
// 128x256-tile ring-3 GEMM over N' = 2N (mode-interleaved weights).
// A [M][K] bf16; Wt [N'][K] bf16; out [M][N'/2] bf16 (phase-blended, opt ELU).
// 8 waves (2M x 4N), per-wave 64x64 (acc=64 VGPR -> 4 waves/SIMD), BK=32,
// ring of 3 LDS buffers (72 KiB -> 2 blocks/CU), st_16x32 swizzle,
// counted vmcnt(3) in steady state, vmcnt(0) drain in the LAST TWO
// iterations (tt+2 >= NT) — closes the R6 tail race where the counted wait
// became a no-op and tile NT-1 could be read before landing.
// ---------------------------------------------------------------------------
template <bool ELU_STORE>
__global__ __launch_bounds__(512, 4) void gemm_ring2(
    const u16* __restrict__ A, const u16* __restrict__ Wt,
    const float* __restrict__ bias, const float2* __restrict__ phase,
    u16* __restrict__ out, int K, int Np) {
  // per buffer: A 128x32 (8 KB) then B 256x32 (16 KB) = 24576 B; ring-3
  __shared__ u16 lds[3][12288];
  const int tnc = Np >> 8;  // 8
  const int nwg = gridDim.x;
  int id = blockIdx.x;
  const int cpx = nwg >> 3;  // nwg % 8 == 0 (2048)
  id = (id & 7) * cpx + (id >> 3);
  const int m0 = (id / tnc) * 128;
  const int n0 = (id % tnc) * 256;
  const int t = threadIdx.x;
  const int lane = t & 63;
  const int wave = t >> 6;
  const int wr = wave >> 2, wc = wave & 3;   // 2M x 4N, wave tile 64x64
  const int lr = lane & 15, ks = lane >> 4;
  // swizzled byte offset within a 1024B (16row x 32col) subtile:
  const int cswz = lr * 64 + (((ks * 8) ^ ((lr >> 3) << 4)) << 1);

  // staging decode (16B chunk q -> logical row/col with inverse swizzle):
  // A: q = t (512 chunks, 8 KB); B: q = ld*512 + t (1024 chunks, 16 KB)
  int soffA, soffB[2];
  {
    int e = t * 8;
    int st = e >> 9, rl = (e >> 5) & 15, c = e & 31;
    soffA = (st * 16 + rl) * K + (c ^ (((rl >> 3) & 1) << 4));
  }
#pragma unroll
  for (int ld = 0; ld < 2; ++ld) {
    int e = (ld * 512 + t) * 8;
    int st = e >> 9, rl = (e >> 5) & 15, c = e & 31;
    soffB[ld] = (st * 16 + rl) * K + (c ^ (((rl >> 3) & 1) << 4));
  }
  const u16* Abase = A + (size_t)m0 * K;
  const u16* Bbase = Wt + (size_t)n0 * K;

  f32x4 acc[4][4] = {};
  const int NT = K >> 5;

  auto stage = [&](int bb, int tile) {
    const int kt = tile << 5;
    char* dst = (char*)&lds[bb][0];
    __builtin_amdgcn_global_load_lds((const AS1 void*)(Abase + kt + soffA),
                                     (AS3 void*)(dst + t * 16), 16, 0, 0);
#pragma unroll
    for (int ld = 0; ld < 2; ++ld)
      __builtin_amdgcn_global_load_lds(
          (const AS1 void*)(Bbase + kt + soffB[ld]),
          (AS3 void*)(dst + 8192 + (ld * 512 + t) * 16), 16, 0, 0);
  };

#define BAR()                    \
  asm volatile("" ::: "memory"); \
  __builtin_amdgcn_s_barrier();  \
  asm volatile("" ::: "memory");

  // A frag m (rows wr*64 + m*16): subtile wr*4 + m. B frag n: subtile wc*4+n.
#define LOADA0(buf)                               \
  _Pragma("unroll") for (int m = 0; m < 2; ++m)   \
      af0[m] = *(const bf16x8*)((const char*)&lds[buf][0] + (((wr * 4 + m) << 10) + cswz));
#define LOADA1(buf)                               \
  _Pragma("unroll") for (int m = 0; m < 2; ++m)   \
      af1[m] = *(const bf16x8*)((const char*)&lds[buf][0] + (((wr * 4 + 2 + m) << 10) + cswz));
#define LOADB(buf)                                \
  _Pragma("unroll") for (int n = 0; n < 4; ++n)   \
      bfr[n] = *(const bf16x8*)((const char*)&lds[buf][0] + 8192 + (((wc * 4 + n) << 10) + cswz));
#define MFMAH(mh, AF)                                                   \
  __builtin_amdgcn_s_setprio(1);                                        \
  _Pragma("unroll") for (int m = 0; m < 2; ++m)                         \
  _Pragma("unroll") for (int n = 0; n < 4; ++n)                         \
      acc[(mh)*2 + m][n] = __builtin_amdgcn_mfma_f32_16x16x32_bf16(     \
          AF[m], bfr[n], acc[(mh)*2 + m][n], 0, 0, 0);                  \
  __builtin_amdgcn_s_setprio(0);

  bf16x8 af0[2], af1[2], bfr[4];

  // prologue: 2 tiles deep; tile 0 landed after vmcnt(3)
  stage(0, 0);
  if (NT > 1) stage(1, 1);
  asm volatile("s_waitcnt vmcnt(3)" ::: "memory");
  BAR();
  LOADA0(0);
  LOADB(0);

  for (int tt = 0; tt < NT; ++tt) {
    const int b = tt % 3;
    // issue second-half A reads; they fly under MFMAH(0)
    LOADA1(b);
    MFMAH(0, af0);                  // consumes af0/bfr (issued pre-barrier)
    if (tt + 2 < NT) {
      stage((tt + 2) % 3, tt + 2);
      // retire tile tt+1's 3 loads (tile tt+2's 3 stay in flight)
      asm volatile("s_waitcnt vmcnt(3)" ::: "memory");
    } else {
      // tail: no stage issued -> counted wait would be a no-op (R6 race).
      // Drain fully so tile NT-1 is guaranteed landed before its reads.
      asm volatile("s_waitcnt vmcnt(0)" ::: "memory");
    }
    MFMAH(1, af1);                  // consumes af1 (overlapped with MFMAH(0))
    BAR();
    // issue next tile's first-half reads; they fly across the loop edge
    if (tt + 1 < NT) {
      const int b2 = (tt + 1) % 3;
      LOADA0(b2);
      LOADB(b2);
    }
  }
#undef LOADA0
#undef LOADA1
#undef LOADB
#undef MFMAH

  // epilogue: nfrags alternate mode0/mode1 over the same 16 real cols.
  const int Nreal = Np >> 1;
  const int colbase = (n0 + wc * 64) >> 1;
  float bias0[2], bias1[2];
#pragma unroll
  for (int pj = 0; pj < 2; ++pj) {
    int ncol = colbase + pj * 16 + lr;
    bias0[pj] = bias[ncol];
    bias1[pj] = bias[Nreal + ncol];
  }
#pragma unroll
  for (int m = 0; m < 4; ++m) {
#pragma unroll
    for (int j = 0; j < 4; ++j) {
      int grow = m0 + wr * 64 + m * 16 + ks * 4 + j;
      float2 ph = phase[grow];
#pragma unroll
      for (int pj = 0; pj < 2; ++pj) {
        int ncol = colbase + pj * 16 + lr;
        float v = ph.x * (acc[m][pj * 2 + 0][j] + bias0[pj]) +
                  ph.y * (acc[m][pj * 2 + 1][j] + bias1[pj]);
        if (ELU_STORE) v = v > 0.f ? v : (__expf(v) - 1.f);
        out[(size_t)grow * Nreal + ncol] = f2bf(v);
      }
    }
  }
#undef BAR
}

// Dual-mode GEMM (layer 3, small N): acc_i = A @ W_i^T, blended epilogue, f32 out
template <int BM, int BN, int WM, int WN, bool ELU_BF16>
__launch_bounds__(256, 2) __global__
void gemm_dualmode(const u16* __restrict__ A, const u16* __restrict__ WT,
                   const float* __restrict__ bias, const float2* __restrict__ phase,
                   void* __restrict__ out, int K, int N) {
  constexpr int MF = WM / 16, NF = WN / 16;
  __shared__ u16 ldsA[BM * 32];
  __shared__ u16 ldsB[2][BN * 32];
  const int m0 = blockIdx.x * BM;
  const int n0 = blockIdx.y * BN;
  const int t = threadIdx.x;
  const int wave = t >> 6, lane = t & 63;
  constexpr int NWC = BN / WN;
  const int wr = wave / NWC, wc = wave % NWC;
  const int lr = lane & 15, ks = lane >> 4;

  f32x4 acc[2][MF][NF] = {};

  for (int kt = 0; kt < K; kt += 32) {
#pragma unroll
    for (int i = 0; i < BM / 64; ++i) {
      int tt = t + i * 256;
      int r = tt >> 2, c8 = (tt & 3) * 8;
      __builtin_amdgcn_global_load_lds(
          (const AS1 void*)(A + (size_t)(m0 + r) * K + kt + c8),
          (AS3 void*)(ldsA + (size_t)tt * 8), 16, 0, 0);
    }
#pragma unroll
    for (int md = 0; md < 2; ++md) {
#pragma unroll
      for (int i = 0; i < BN / 64; ++i) {
        int tt = t + i * 256;
        int r = tt >> 2, c8 = (tt & 3) * 8;
        __builtin_amdgcn_global_load_lds(
            (const AS1 void*)(WT + (size_t)md * N * K + (size_t)(n0 + r) * K + kt + c8),
            (AS3 void*)(ldsB[md] + (size_t)tt * 8), 16, 0, 0);
      }
    }
    __syncthreads();

    bf16x8 af[MF], b0f[NF], b1f[NF];
#pragma unroll
    for (int m = 0; m < MF; ++m)
      af[m] = *reinterpret_cast<const bf16x8*>(&ldsA[(wr * WM + m * 16 + lr) * 32 + ks * 8]);
#pragma unroll
    for (int n = 0; n < NF; ++n) {
      b0f[n] = *reinterpret_cast<const bf16x8*>(&ldsB[0][(wc * WN + n * 16 + lr) * 32 + ks * 8]);
      b1f[n] = *reinterpret_cast<const bf16x8*>(&ldsB[1][(wc * WN + n * 16 + lr) * 32 + ks * 8]);
    }
#pragma unroll
    for (int m = 0; m < MF; ++m) {
#pragma unroll
      for (int n = 0; n < NF; ++n) {
        acc[0][m][n] = __builtin_amdgcn_mfma_f32_16x16x32_bf16(af[m], b0f[n], acc[0][m][n], 0, 0, 0);
        acc[1][m][n] = __builtin_amdgcn_mfma_f32_16x16x32_bf16(af[m], b1f[n], acc[1][m][n], 0, 0, 0);
      }
    }
    __syncthreads();
  }

#pragma unroll
  for (int m = 0; m < MF; ++m) {
#pragma unroll
    for (int j = 0; j < 4; ++j) {
      int grow = m0 + wr * WM + m * 16 + ks * 4 + j;
      float2 ph = phase[grow];
#pragma unroll
      for (int n = 0; n < NF; ++n) {
        int gcol = n0 + wc * WN + n * 16 + lr;
        float v = ph.x * (acc[0][m][n][j] + bias[gcol]) +
                  ph.y * (acc[1][m][n][j] + bias[N + gcol]);
        if (ELU_BF16) {
          v = v > 0.f ? v : (__expf(v) - 1.f);
          ((u16*)out)[(size_t)grow * N + gcol] = f2bf(v);
        } else {
          ((float*)out)[(size_t)grow * N + gcol] = v;
        }
      }
    }
  }
}

extern "C" void kernel_launch(void* const* d_in, const int* in_sizes, int n_in,
                              void* d_out, int out_size, void* d_ws, size_t ws_size,
                              hipStream_t stream) {
  const float* x  = (const float*)d_in[0];
  const float* w1 = (const float*)d_in[1];
  const float* b1 = (const float*)d_in[2];
  const float* w2 = (const float*)d_in[3];
  const float* b2 = (const float*)d_in[4];
  const float* w3 = (const float*)d_in[5];
  const float* b3 = (const float*)d_in[6];
  float* out = (float*)d_out;
  const int B = 32768, DIN = 256, H = 1024, DOUT = 64;

  char* ws = (char*)d_ws;
  u16* W1Ti = (u16*)ws;    ws += (size_t)2 * H * DIN * 2;   // [2048][256]
  u16* W2Ti = (u16*)ws;    ws += (size_t)2 * H * H * 2;     // [2048][1024]
  u16* W3T = (u16*)ws;     ws += (size_t)2 * DOUT * H * 2;  // [2][64][1024]
  float2* phase = (float2*)ws; ws += (size_t)B * 8;
  u16* hx = (u16*)ws;      ws += (size_t)B * DIN * 2;
  u16* h1 = (u16*)ws;      ws += (size_t)B * H * 2;
  u16* h2 = (u16*)ws;      ws += (size_t)B * H * 2;

  prep_x_kernel<<<(B * 128 + 255) / 256, 256, 0, stream>>>(x, hx, phase, B);
  prep_w_int_kernel<<<dim3(DIN / 64, H / 64, 2), 256, 0, stream>>>(w1, W1Ti, DIN, H);
  prep_w_int_kernel<<<dim3(H / 64, H / 64, 2), 256, 0, stream>>>(w2, W2Ti, H, H);
  prep_w_kernel<<<dim3(H / 64, DOUT / 64, 2), 256, 0, stream>>>(w3, W3T, H, DOUT);

  const int nwg = (B / 128) * (2 * H / 256);  // 256 * 8 = 2048
  gemm_ring2<true><<<nwg, 512, 0, stream>>>(hx, W1Ti, b1, phase, h1, DIN, 2 * H);
  gemm_ring2<true><<<nwg, 512, 0, stream>>>(h1, W2Ti, b2, phase, h2, H, 2 * H);
  gemm_dualmode<128, 64, 64, 32, false>
      <<<dim3(B / 128, DOUT / 64), 256, 0, stream>>>(h2, W3T, b3, phase, out, H, DOUT);
}

// Round 9
// 238.716 us; speedup vs baseline: 1.0224x; 1.0224x over previous
//
#include <hip/hip_runtime.h>

typedef unsigned short u16;
typedef __bf16 bf16x8 __attribute__((ext_vector_type(8)));
typedef float f32x4 __attribute__((ext_vector_type(4)));

#define AS1 __attribute__((address_space(1)))
#define AS3 __attribute__((address_space(3)))

static __device__ __forceinline__ u16 f2bf(float f) {
  union { float f; unsigned u; } v; v.f = f;
  unsigned r = (v.u + 0x7fff + ((v.u >> 16) & 1)) >> 16;
  return (u16)r;
}

// x [B][258] f32 -> hx [B][256] bf16, phase [B] float2
__global__ void prep_x_kernel(const float* __restrict__ x, u16* __restrict__ hx,
                              float2* __restrict__ phase, int B) {
  int i = blockIdx.x * blockDim.x + threadIdx.x;
  int total = B * 128;
  if (i < total) {
    int row = i >> 7, k2 = (i & 127);
    const float2 v = *reinterpret_cast<const float2*>(x + (size_t)row * 258 + k2 * 2);
    u16 a = f2bf(v.x), b = f2bf(v.y);
    *reinterpret_cast<unsigned*>(hx + (size_t)row * 256 + k2 * 2) =
        (unsigned)a | ((unsigned)b << 16);
  }
  if (i < B) {
    phase[i] = *reinterpret_cast<const float2*>(x + (size_t)i * 258 + 256);
  }
}

// w [2][K][N] f32 -> wt [2][N][K] bf16 (plain transposed layout, for layer 3)
__global__ void prep_w_kernel(const float* __restrict__ w, u16* __restrict__ wt,
                              int K, int N) {
  __shared__ u16 tile[64][65];
  int k0 = blockIdx.x * 64, n0 = blockIdx.y * 64, mode = blockIdx.z;
  const float* src = w + (size_t)mode * K * N;
  u16* dst = wt + (size_t)mode * N * K;
  int c = threadIdx.x & 63;
  int r4 = threadIdx.x >> 6;
#pragma unroll
  for (int i = 0; i < 16; ++i) {
    int r = r4 + i * 4;
    tile[r][c] = f2bf(src[(size_t)(k0 + r) * N + n0 + c]);
  }
  __syncthreads();
#pragma unroll
  for (int i = 0; i < 16; ++i) {
    int r = r4 + i * 4;  // n index offset
    dst[(size_t)(n0 + r) * K + k0 + c] = tile[c][r];
  }
}

// w [2][K][N] f32 -> wt' [2N][K] bf16, mode-interleaved by 16-col groups:
// n' = (n>>4)*32 + mode*16 + (n&15)
__global__ void prep_w_int_kernel(const float* __restrict__ w, u16* __restrict__ wt,
                                  int K, int N) {
  __shared__ u16 tile[64][65];
  int k0 = blockIdx.x * 64, n0 = blockIdx.y * 64, mode = blockIdx.z;
  const float* src = w + (size_t)mode * K * N;
  int c = threadIdx.x & 63;
  int r4 = threadIdx.x >> 6;
#pragma unroll
  for (int i = 0; i < 16; ++i) {
    int r = r4 + i * 4;
    tile[r][c] = f2bf(src[(size_t)(k0 + r) * N + n0 + c]);
  }
  __syncthreads();
#pragma unroll
  for (int i = 0; i < 16; ++i) {
    int n = n0 + r4 + i * 4;
    int np = ((n >> 4) << 5) + (mode << 4) + (n & 15);
    wt[(size_t)np * K + k0 + c] = tile[c][r4 + i * 4];
  }
}

// ---------------------------------------------------------------------------
// 256x256-tile GEMM over N' = 2N, m201-style phase bracket.
// 8 waves (2M x 4N), wave tile 128x64, BK=32, ring-4 LDS (128 KiB),
// st_16x32 swizzle. Iteration = 2 K-tiles = 4 phases; each phase:
//   {ds_reads, 2-gload stage chunk, [counted vmcnt], barrier, lgkmcnt(0),
//    setprio(1), 16 MFMA, setprio(0), barrier}
// INVARIANT (R8 lesson): every ds_read of a tile is separated from the
// per-wave vmcnt that guarantees the tile landed by a BARRIER — the wait
// goes at the END of phases 1/3, before the barrier that precedes the
// next tile's first reads. Tail: vmcnt(0) (R6 lesson).
// ---------------------------------------------------------------------------
template <bool ELU_STORE>
__global__ __launch_bounds__(512, 2) void gemm_4ph(
    const u16* __restrict__ A, const u16* __restrict__ Wt,
    const float* __restrict__ bias, const float2* __restrict__ phase,
    u16* __restrict__ out, int K, int Np) {
  __shared__ u16 lds[4][2][8192];  // [ring buf][A|B][256 rows x 32 cols swz]
  const int tnc = Np >> 8;  // 8
  const int nwg = gridDim.x;
  int id = blockIdx.x;
  const int cpx = nwg >> 3;  // nwg % 8 == 0 (1024)
  id = (id & 7) * cpx + (id >> 3);
  const int m0 = (id / tnc) * 256;
  const int n0 = (id % tnc) * 256;
  const int t = threadIdx.x;
  const int lane = t & 63;
  const int wave = t >> 6;
  const int wr = wave >> 2, wc = wave & 3;  // wave tile 128x64
  const int lr = lane & 15, ks = lane >> 4;
  // swizzled byte offset within a 1024B (16row x 32col) subtile:
  const int cswz = lr * 64 + (((ks * 8) ^ ((lr >> 3) << 4)) << 1);

  // staging decode (16B chunk q = ld*512 + t -> row/col with inverse swizzle)
  int soff[2];
#pragma unroll
  for (int ld = 0; ld < 2; ++ld) {
    int e = (ld * 512 + t) * 8;
    int st = e >> 9, rl = (e >> 5) & 15, c = e & 31;
    soff[ld] = (st * 16 + rl) * K + (c ^ (((rl >> 3) & 1) << 4));
  }
  const u16* Abase = A + (size_t)m0 * K;
  const u16* Bbase = Wt + (size_t)n0 * K;

  f32x4 acc[8][4] = {};
  const int NT = K >> 5;  // K32 tiles (8 or 32; always even, >= 4)

  // stage one matrix half-chunk: 2 gloads (16 KB)
  auto stageA = [&](int bb, int tile) {
    const int kt = tile << 5;
#pragma unroll
    for (int ld = 0; ld < 2; ++ld)
      __builtin_amdgcn_global_load_lds(
          (const AS1 void*)(Abase + kt + soff[ld]),
          (AS3 void*)(&lds[bb][0][(ld * 512 + t) * 8]), 16, 0, 0);
  };
  auto stageB = [&](int bb, int tile) {
    const int kt = tile << 5;
#pragma unroll
    for (int ld = 0; ld < 2; ++ld)
      __builtin_amdgcn_global_load_lds(
          (const AS1 void*)(Bbase + kt + soff[ld]),
          (AS3 void*)(&lds[bb][1][(ld * 512 + t) * 8]), 16, 0, 0);
  };

#define BAR()                    \
  asm volatile("" ::: "memory"); \
  __builtin_amdgcn_s_barrier();  \
  asm volatile("" ::: "memory");

#define LOADA0(buf)                               \
  _Pragma("unroll") for (int m = 0; m < 4; ++m)   \
      af0[m] = *(const bf16x8*)((const char*)&lds[buf][0][0] + (((wr * 8 + m) << 10) + cswz));
#define LOADA1(buf)                               \
  _Pragma("unroll") for (int m = 0; m < 4; ++m)   \
      af1[m] = *(const bf16x8*)((const char*)&lds[buf][0][0] + (((wr * 8 + 4 + m) << 10) + cswz));
#define LOADB(buf)                                \
  _Pragma("unroll") for (int n = 0; n < 4; ++n)   \
      bfr[n] = *(const bf16x8*)((const char*)&lds[buf][1][0] + (((wc * 4 + n) << 10) + cswz));
#define MFMA16(mh, AF)                                                  \
  __builtin_amdgcn_s_setprio(1);                                        \
  _Pragma("unroll") for (int m = 0; m < 4; ++m)                         \
  _Pragma("unroll") for (int n = 0; n < 4; ++n)                         \
      acc[(mh)*4 + m][n] = __builtin_amdgcn_mfma_f32_16x16x32_bf16(     \
          AF[m], bfr[n], acc[(mh)*4 + m][n], 0, 0, 0);                  \
  __builtin_amdgcn_s_setprio(0);

  bf16x8 af0[4], af1[4], bfr[4];

  // prologue: fully stage tiles 0 and 1 (8 loads); guarantee tile 0 landed
  // for ALL waves: per-wave vmcnt(4) then barrier.
  stageA(0, 0);
  stageB(0, 0);
  stageA(1, 1);
  stageB(1, 1);
  asm volatile("s_waitcnt vmcnt(4)" ::: "memory");
  BAR();

  for (int u = 0; u < NT; u += 2) {
    const int bu = u & 3, bu1 = (u + 1) & 3;
    const bool last = (u + 2) >= NT;
    // ---- phase 0: tile u, mh=0 (tile u landed: prior vmcnt+BAR) ----
    LOADA0(bu);
    LOADB(bu);
    if (!last) stageA((u + 2) & 3, u + 2);
    BAR();
    asm volatile("s_waitcnt lgkmcnt(0)" ::: "memory");
    MFMA16(0, af0);
    BAR();
    // ---- phase 1: tile u, mh=1; end-wait covers tile u+1 ----
    LOADA1(bu);
    if (!last) {
      stageB((u + 2) & 3, u + 2);
      // outstanding = tile u+1 (4) + tile u+2 (4); retire tile u+1
      asm volatile("s_waitcnt vmcnt(4)" ::: "memory");
    } else {
      // no stages this iter: counted wait would no-op; drain (R6 lesson)
      asm volatile("s_waitcnt vmcnt(0)" ::: "memory");
    }
    BAR();
    asm volatile("s_waitcnt lgkmcnt(0)" ::: "memory");
    MFMA16(1, af1);
    BAR();
    // ---- phase 2: tile u+1, mh=0 (landed per phase-1 wait+BAR) ----
    LOADA0(bu1);
    LOADB(bu1);
    if (!last) stageA((u + 3) & 3, u + 3);
    BAR();
    asm volatile("s_waitcnt lgkmcnt(0)" ::: "memory");
    MFMA16(0, af0);
    BAR();
    // ---- phase 3: tile u+1, mh=1; end-wait covers tile u+2 ----
    LOADA1(bu1);
    if (!last) {
      stageB((u + 3) & 3, u + 3);
      // outstanding = tile u+2 (4) + tile u+3 (4); retire tile u+2
      asm volatile("s_waitcnt vmcnt(4)" ::: "memory");
    }
    BAR();
    asm volatile("s_waitcnt lgkmcnt(0)" ::: "memory");
    MFMA16(1, af1);
    BAR();
  }
#undef LOADA0
#undef LOADA1
#undef LOADB
#undef MFMA16

  // epilogue: blend mode pairs with phase, add bias, optional ELU, bf16 store
  const int Nreal = Np >> 1;
  const int colbase = (n0 + wc * 64) >> 1;
  float bias0[2], bias1[2];
#pragma unroll
  for (int pj = 0; pj < 2; ++pj) {
    int ncol = colbase + pj * 16 + lr;
    bias0[pj] = bias[ncol];
    bias1[pj] = bias[Nreal + ncol];
  }
#pragma unroll
  for (int m = 0; m < 8; ++m) {
#pragma unroll
    for (int j = 0; j < 4; ++j) {
      int grow = m0 + wr * 128 + m * 16 + ks * 4 + j;
      float2 ph = phase[grow];
#pragma unroll
      for (int pj = 0; pj < 2; ++pj) {
        int ncol = colbase + pj * 16 + lr;
        float v = ph.x * (acc[m][pj * 2 + 0][j] + bias0[pj]) +
                  ph.y * (acc[m][pj * 2 + 1][j] + bias1[pj]);
        if (ELU_STORE) v = v > 0.f ? v : (__expf(v) - 1.f);
        out[(size_t)grow * Nreal + ncol] = f2bf(v);
      }
    }
  }
#undef BAR
}

// Dual-mode GEMM (layer 3, small N): acc_i = A @ W_i^T, blended epilogue, f32 out
template <int BM, int BN, int WM, int WN, bool ELU_BF16>
__launch_bounds__(256, 2) __global__
void gemm_dualmode(const u16* __restrict__ A, const u16* __restrict__ WT,
                   const float* __restrict__ bias, const float2* __restrict__ phase,
                   void* __restrict__ out, int K, int N) {
  constexpr int MF = WM / 16, NF = WN / 16;
  __shared__ u16 ldsA[BM * 32];
  __shared__ u16 ldsB[2][BN * 32];
  const int m0 = blockIdx.x * BM;
  const int n0 = blockIdx.y * BN;
  const int t = threadIdx.x;
  const int wave = t >> 6, lane = t & 63;
  constexpr int NWC = BN / WN;
  const int wr = wave / NWC, wc = wave % NWC;
  const int lr = lane & 15, ks = lane >> 4;

  f32x4 acc[2][MF][NF] = {};

  for (int kt = 0; kt < K; kt += 32) {
#pragma unroll
    for (int i = 0; i < BM / 64; ++i) {
      int tt = t + i * 256;
      int r = tt >> 2, c8 = (tt & 3) * 8;
      __builtin_amdgcn_global_load_lds(
          (const AS1 void*)(A + (size_t)(m0 + r) * K + kt + c8),
          (AS3 void*)(ldsA + (size_t)tt * 8), 16, 0, 0);
    }
#pragma unroll
    for (int md = 0; md < 2; ++md) {
#pragma unroll
      for (int i = 0; i < BN / 64; ++i) {
        int tt = t + i * 256;
        int r = tt >> 2, c8 = (tt & 3) * 8;
        __builtin_amdgcn_global_load_lds(
            (const AS1 void*)(WT + (size_t)md * N * K + (size_t)(n0 + r) * K + kt + c8),
            (AS3 void*)(ldsB[md] + (size_t)tt * 8), 16, 0, 0);
      }
    }
    __syncthreads();

    bf16x8 af[MF], b0f[NF], b1f[NF];
#pragma unroll
    for (int m = 0; m < MF; ++m)
      af[m] = *reinterpret_cast<const bf16x8*>(&ldsA[(wr * WM + m * 16 + lr) * 32 + ks * 8]);
#pragma unroll
    for (int n = 0; n < NF; ++n) {
      b0f[n] = *reinterpret_cast<const bf16x8*>(&ldsB[0][(wc * WN + n * 16 + lr) * 32 + ks * 8]);
      b1f[n] = *reinterpret_cast<const bf16x8*>(&ldsB[1][(wc * WN + n * 16 + lr) * 32 + ks * 8]);
    }
#pragma unroll
    for (int m = 0; m < MF; ++m) {
#pragma unroll
      for (int n = 0; n < NF; ++n) {
        acc[0][m][n] = __builtin_amdgcn_mfma_f32_16x16x32_bf16(af[m], b0f[n], acc[0][m][n], 0, 0, 0);
        acc[1][m][n] = __builtin_amdgcn_mfma_f32_16x16x32_bf16(af[m], b1f[n], acc[1][m][n], 0, 0, 0);
      }
    }
    __syncthreads();
  }

#pragma unroll
  for (int m = 0; m < MF; ++m) {
#pragma unroll
    for (int j = 0; j < 4; ++j) {
      int grow = m0 + wr * WM + m * 16 + ks * 4 + j;
      float2 ph = phase[grow];
#pragma unroll
      for (int n = 0; n < NF; ++n) {
        int gcol = n0 + wc * WN + n * 16 + lr;
        float v = ph.x * (acc[0][m][n][j] + bias[gcol]) +
                  ph.y * (acc[1][m][n][j] + bias[N + gcol]);
        if (ELU_BF16) {
          v = v > 0.f ? v : (__expf(v) - 1.f);
          ((u16*)out)[(size_t)grow * N + gcol] = f2bf(v);
        } else {
          ((float*)out)[(size_t)grow * N + gcol] = v;
        }
      }
    }
  }
}

extern "C" void kernel_launch(void* const* d_in, const int* in_sizes, int n_in,
                              void* d_out, int out_size, void* d_ws, size_t ws_size,
                              hipStream_t stream) {
  const float* x  = (const float*)d_in[0];
  const float* w1 = (const float*)d_in[1];
  const float* b1 = (const float*)d_in[2];
  const float* w2 = (const float*)d_in[3];
  const float* b2 = (const float*)d_in[4];
  const float* w3 = (const float*)d_in[5];
  const float* b3 = (const float*)d_in[6];
  float* out = (float*)d_out;
  const int B = 32768, DIN = 256, H = 1024, DOUT = 64;

  char* ws = (char*)d_ws;
  u16* W1Ti = (u16*)ws;    ws += (size_t)2 * H * DIN * 2;   // [2048][256]
  u16* W2Ti = (u16*)ws;    ws += (size_t)2 * H * H * 2;     // [2048][1024]
  u16* W3T = (u16*)ws;     ws += (size_t)2 * DOUT * H * 2;  // [2][64][1024]
  float2* phase = (float2*)ws; ws += (size_t)B * 8;
  u16* hx = (u16*)ws;      ws += (size_t)B * DIN * 2;
  u16* h1 = (u16*)ws;      ws += (size_t)B * H * 2;
  u16* h2 = (u16*)ws;      ws += (size_t)B * H * 2;

  prep_x_kernel<<<(B * 128 + 255) / 256, 256, 0, stream>>>(x, hx, phase, B);
  prep_w_int_kernel<<<dim3(DIN / 64, H / 64, 2), 256, 0, stream>>>(w1, W1Ti, DIN, H);
  prep_w_int_kernel<<<dim3(H / 64, H / 64, 2), 256, 0, stream>>>(w2, W2Ti, H, H);
  prep_w_kernel<<<dim3(H / 64, DOUT / 64, 2), 256, 0, stream>>>(w3, W3T, H, DOUT);

  const int nwg = (B / 256) * (2 * H / 256);  // 128 * 8 = 1024
  gemm_4ph<true><<<nwg, 512, 0, stream>>>(hx, W1Ti, b1, phase, h1, DIN, 2 * H);
  gemm_4ph<true><<<nwg, 512, 0, stream>>>(h1, W2Ti, b2, phase, h2, H, 2 * H);
  gemm_dualmode<128, 64, 64, 32, false>
      <<<dim3(B / 128, DOUT / 64), 256, 0, stream>>>(h2, W3T, b3, phase, out, H, DOUT);
}